// Round 4
// baseline (279.062 us; speedup 1.0000x reference)
//
#include <hip/hip_runtime.h>
#include <hip/hip_bf16.h>

typedef __bf16 bf16x8 __attribute__((ext_vector_type(8)));
typedef __bf16 bf16x4 __attribute__((ext_vector_type(4)));
typedef float  f32x4  __attribute__((ext_vector_type(4)));

#define MFMA_BF16(a, b, c) __builtin_amdgcn_mfma_f32_16x16x32_bf16((a), (b), (c), 0, 0, 0)

#define GLOAD_LDS16(g, l)                                          \
  __builtin_amdgcn_global_load_lds(                                \
      (const __attribute__((address_space(1))) void*)(g),          \
      (__attribute__((address_space(3))) void*)(l), 16, 0, 0)

static constexpr int kDim = 1024;
static constexpr int kHeads = 16;
static constexpr int kB = 4;
static constexpr int kNQ = 1024;
static constexpr int kNKV = 1024;

// ---------------------------------------------------------------------------
// fp32 -> bf16 canonicalization (fp32 inputs confirmed r1/r2).
// ---------------------------------------------------------------------------
struct Conv6 {
  const float* src[6];
  __bf16* dst[6];
  int n4[6];
};
__global__ __launch_bounds__(256) void convert6(Conv6 a) {
  const int w = blockIdx.y;
  const float4* __restrict__ s = (const float4*)a.src[w];
  __bf16* __restrict__ d = a.dst[w];
  const int n4 = a.n4[w];
  const int stride = gridDim.x * blockDim.x;
  for (int i = blockIdx.x * blockDim.x + threadIdx.x; i < n4; i += stride) {
    const float4 v = s[i];
    bf16x4 o = {(__bf16)v.x, (__bf16)v.y, (__bf16)v.z, (__bf16)v.w};
    *(bf16x4*)(d + (size_t)i * 4) = o;
  }
}

// ---------------------------------------------------------------------------
// QKV NT-GEMM (unchanged from r3 — known good, <75us, will profile when top).
// ---------------------------------------------------------------------------
struct QKVArgs {
  const __bf16* A[3];
  const __bf16* W[3];
  const float* bias[3];
  const float* rel;
  __bf16* out[3];
};

__global__ __launch_bounds__(256) void qkv_gemm(QKVArgs args) {
  constexpr int K = kDim;
  __shared__ __bf16 As[128 * 32];
  __shared__ __bf16 Bs[128 * 32];
  const int z = blockIdx.z;  // 0=Q, 1=K, 2=V
  const __bf16* __restrict__ A = args.A[z];
  const __bf16* __restrict__ W = args.W[z];
  const float* __restrict__ bias = args.bias[z];
  const float* __restrict__ rel = args.rel;
  __bf16* __restrict__ out = args.out[z];

  const int tid = threadIdx.x;
  const int wave = tid >> 6, lane = tid & 63;
  const int lr = lane & 15, quad = lane >> 4;
  const int wm = (wave & 1) << 6, wn = (wave >> 1) << 6;
  const int m0 = blockIdx.y << 7, n0 = blockIdx.x << 7;

  f32x4 acc[4][4] = {};

  for (int k0 = 0; k0 < K; k0 += 32) {
    __syncthreads();
#pragma unroll
    for (int i = 0; i < 2; ++i) {
      const int ch = tid + (i << 8);
      const int row = ch >> 2, col = (ch & 3) << 3;
      GLOAD_LDS16(A + (size_t)(m0 + row) * K + k0 + col, As + ch * 8);
      GLOAD_LDS16(W + (size_t)(n0 + row) * K + k0 + col, Bs + ch * 8);
    }
    __syncthreads();
    bf16x8 afr[4], bfr[4];
#pragma unroll
    for (int mi = 0; mi < 4; ++mi)
      afr[mi] = *(const bf16x8*)&As[(wm + mi * 16 + lr) * 32 + quad * 8];
#pragma unroll
    for (int ni = 0; ni < 4; ++ni)
      bfr[ni] = *(const bf16x8*)&Bs[(wn + ni * 16 + lr) * 32 + quad * 8];
#pragma unroll
    for (int mi = 0; mi < 4; ++mi)
#pragma unroll
      for (int ni = 0; ni < 4; ++ni)
        acc[mi][ni] = MFMA_BF16(afr[mi], bfr[ni], acc[mi][ni]);
  }

#pragma unroll
  for (int mi = 0; mi < 4; ++mi)
#pragma unroll
    for (int ni = 0; ni < 4; ++ni) {
      const int col = n0 + wn + ni * 16 + lr;
      const float bc = bias[col];
      const f32x4 v = acc[mi][ni];
#pragma unroll
      for (int r = 0; r < 4; ++r) {
        const int row = m0 + wm + mi * 16 + (quad << 2) + r;
        const float val = v[r] + bc;
        const int bb = row >> 10, nn = row & 1023;
        const int hh = col >> 6, dd = col & 63;
        if (z == 0) {
          out[(((size_t)(bb * kHeads + hh) << 10) + nn) * 64 + dd] = (__bf16)val;
        } else if (z == 1) {
          const float rv = rel[(bb << 10) + nn];
          out[(((size_t)(bb * kHeads + hh) << 10) + nn) * 64 + dd] = (__bf16)(val * rv);
        } else {
          const float rv = rel[(bb << 10) + nn];
          out[(((size_t)(bb * kHeads + hh) << 6) + dd) * (size_t)kNKV + nn] =
              (__bf16)(val * rv);
        }
      }
    }
}

// O-projection: fp32 output straight to d_out (unchanged from r3).
__global__ __launch_bounds__(256) void o_gemm(const __bf16* __restrict__ A,
                                              const __bf16* __restrict__ W,
                                              const float* __restrict__ bias,
                                              float* __restrict__ out) {
  constexpr int K = kDim;
  __shared__ __bf16 As[128 * 32];
  __shared__ __bf16 Bs[128 * 32];
  const int tid = threadIdx.x;
  const int wave = tid >> 6, lane = tid & 63;
  const int lr = lane & 15, quad = lane >> 4;
  const int wm = (wave & 1) << 6, wn = (wave >> 1) << 6;
  const int m0 = blockIdx.y << 7, n0 = blockIdx.x << 7;

  f32x4 acc[4][4] = {};
  for (int k0 = 0; k0 < K; k0 += 32) {
    __syncthreads();
#pragma unroll
    for (int i = 0; i < 2; ++i) {
      const int ch = tid + (i << 8);
      const int row = ch >> 2, col = (ch & 3) << 3;
      GLOAD_LDS16(A + (size_t)(m0 + row) * K + k0 + col, As + ch * 8);
      GLOAD_LDS16(W + (size_t)(n0 + row) * K + k0 + col, Bs + ch * 8);
    }
    __syncthreads();
    bf16x8 afr[4], bfr[4];
#pragma unroll
    for (int mi = 0; mi < 4; ++mi)
      afr[mi] = *(const bf16x8*)&As[(wm + mi * 16 + lr) * 32 + quad * 8];
#pragma unroll
    for (int ni = 0; ni < 4; ++ni)
      bfr[ni] = *(const bf16x8*)&Bs[(wn + ni * 16 + lr) * 32 + quad * 8];
#pragma unroll
    for (int mi = 0; mi < 4; ++mi)
#pragma unroll
      for (int ni = 0; ni < 4; ++ni)
        acc[mi][ni] = MFMA_BF16(afr[mi], bfr[ni], acc[mi][ni]);
  }
#pragma unroll
  for (int mi = 0; mi < 4; ++mi)
#pragma unroll
    for (int ni = 0; ni < 4; ++ni) {
      const int col = n0 + wn + ni * 16 + lr;
      const float bc = bias[col];
      const f32x4 v = acc[mi][ni];
#pragma unroll
      for (int r = 0; r < 4; ++r) {
        const int row = m0 + wm + mi * 16 + (quad << 2) + r;
        out[(size_t)row * kDim + col] = v[r] + bc;
      }
    }
}

// ---------------------------------------------------------------------------
// Attention v3: WG = (b, h, 32 q-rows), 512 threads = 8 waves, S = 64 KB bf16.
//  - Phase 1 MFMA transposed (A=K rows, B=Q rows -> D[kv][q]): lane holds 4
//    consecutive kv for one q-row -> single packed 8B LDS store; reliability
//    applied as multiply (exp(s+log r) == clip(r)*exp(s)) -> no __logf.
//  - Swizzle: S[q][kv] at q*1024 + ((chunk ^ (q&7))*8) + kv%8, chunk=kv/8.
//  - Phase 3: wave = (d-tile = w>>1, q-half = w&1); ones-MFMA gives row sums.
//  - Occupancy: 2 WG x 8 waves = 16 waves/CU (was 8).
// ---------------------------------------------------------------------------
__global__ __launch_bounds__(512, 4) void attn32(const __bf16* __restrict__ Qb,
                                                 const __bf16* __restrict__ Kb,
                                                 const __bf16* __restrict__ Vb,
                                                 const float* __restrict__ rel,
                                                 __bf16* __restrict__ AO) {
  __shared__ __bf16 S[32 * 1024];  // 64 KB
  const int tid = threadIdx.x;
  const int wave = tid >> 6, lane = tid & 63;
  const int lr = lane & 15, quad = lane >> 4;
  const int bid = blockIdx.x;
  const int b = bid >> 9, rem = bid & 511;
  const int h = rem >> 5, q0 = (rem & 31) << 5;
  const __bf16* Qh = Qb + ((size_t)(b * kHeads + h) << 16);  // [n][64]
  const __bf16* Kh = Kb + ((size_t)(b * kHeads + h) << 16);  // [n][64] (r folded)
  const __bf16* Vh = Vb + ((size_t)(b * kHeads + h) << 16);  // [64][n] (r folded)
  const float* rb = rel + (b << 10);

  // Q as B-fragments: B[n = q-row = lane&15][k = quad*8+j], two 32-k steps
  bf16x8 qfrag[2][2];
#pragma unroll
  for (int mt = 0; mt < 2; ++mt) {
    const __bf16* qrow = Qh + (q0 + mt * 16 + lr) * 64 + quad * 8;
    qfrag[mt][0] = *(const bf16x8*)qrow;
    qfrag[mt][1] = *(const bf16x8*)(qrow + 32);
  }

  // Phase 1: D[kv][q] = K.Q^T; p = clip(r)*exp(s*0.125); packed b64 stores.
  for (int i = 0; i < 8; ++i) {
    const int n0 = ((i << 3) + wave) << 4;  // wave w covers kv-tiles w+8j
    const __bf16* krow = Kh + (n0 + lr) * 64 + quad * 8;
    const bf16x8 ka0 = *(const bf16x8*)krow;
    const bf16x8 ka1 = *(const bf16x8*)(krow + 32);
    const int kvb = n0 + (quad << 2);      // lane's 4 consecutive kv
    const f32x4 rcv = *(const f32x4*)(rb + kvb);
    const int cb = kvb >> 3, k7 = kvb & 7;
#pragma unroll
    for (int mt = 0; mt < 2; ++mt) {
      f32x4 acc = {0.f, 0.f, 0.f, 0.f};
      acc = MFMA_BF16(ka0, qfrag[mt][0], acc);
      acc = MFMA_BF16(ka1, qfrag[mt][1], acc);
      const int q = (mt << 4) + lr;        // D col = lane&15 = q-row
      bf16x4 pk;
#pragma unroll
      for (int r = 0; r < 4; ++r)          // D row = quad*4+r = kv
        pk[r] = (__bf16)(fmaxf(rcv[r], 1e-6f) * __expf(acc[r] * 0.125f));
      *(bf16x4*)&S[(q << 10) + ((cb ^ (q & 7)) << 3) + k7] = pk;
    }
  }
  __syncthreads();

  // Phase 3: wave = (d-tile, q-half). O = P V'^T, L via ones-MFMA.
  bf16x8 ones;
#pragma unroll
  for (int j = 0; j < 8; ++j) ones[j] = (__bf16)1.0f;
  const int dt = wave >> 1, mt = wave & 1;
  const __bf16* vrow = Vh + (size_t)((dt << 4) + lr) * kNKV;
  const int row = (mt << 4) + lr, xr = lr & 7;
  const int sbase = row << 10;
  f32x4 accO = {0.f, 0.f, 0.f, 0.f};
  f32x4 accL = {0.f, 0.f, 0.f, 0.f};
  for (int kk = 0; kk < 32; ++kk) {
    const int c = (kk << 2) + quad;
    const bf16x8 af = *(const bf16x8*)&S[sbase + ((c ^ xr) << 3)];
    const bf16x8 bv = *(const bf16x8*)(vrow + (kk << 5) + (quad << 3));
    accO = MFMA_BF16(af, bv, accO);
    accL = MFMA_BF16(af, ones, accL);
  }
  // D: row(q) = quad*4+r, col(d) = lane&15
  const int dcol = (h << 6) + (dt << 4) + lr;
  const size_t ob = (size_t)(b << 10) + q0 + (mt << 4);
#pragma unroll
  for (int r = 0; r < 4; ++r)
    AO[(ob + (quad << 2) + r) * kDim + dcol] = (__bf16)(accO[r] / accL[r]);
}

extern "C" void kernel_launch(void* const* d_in, const int* in_sizes, int n_in,
                              void* d_out, int out_size, void* d_ws, size_t ws_size,
                              hipStream_t stream) {
  (void)in_sizes; (void)n_in; (void)out_size; (void)ws_size;
  const float* qf  = (const float*)d_in[0];
  const float* kvf = (const float*)d_in[1];
  const float* rel = (const float*)d_in[2];
  const float* Wq  = (const float*)d_in[3];
  const float* bq  = (const float*)d_in[4];
  const float* Wk  = (const float*)d_in[5];
  const float* bk  = (const float*)d_in[6];
  const float* Wv  = (const float*)d_in[7];
  const float* bv  = (const float*)d_in[8];
  const float* Wo  = (const float*)d_in[9];
  const float* bo  = (const float*)d_in[10];

  const size_t big = (size_t)kB * kNQ * kDim;  // 4M elements
  __bf16* p = (__bf16*)d_ws;
  __bf16* cqf  = p; p += big;
  __bf16* ckvf = p; p += big;
  __bf16* cWq  = p; p += kDim * kDim;
  __bf16* cWk  = p; p += kDim * kDim;
  __bf16* cWv  = p; p += kDim * kDim;
  __bf16* cWo  = p; p += kDim * kDim;
  __bf16* q_buf  = p; p += big;
  __bf16* k_buf  = p; p += big;
  __bf16* vT_buf = p; p += big;
  __bf16* ao_buf = p; p += big;

  Conv6 cv;
  const float* srcs[6] = {qf, kvf, Wq, Wk, Wv, Wo};
  __bf16* dsts[6] = {cqf, ckvf, cWq, cWk, cWv, cWo};
  const int n4s[6] = {(int)(big >> 2), (int)(big >> 2),
                      kDim * kDim / 4, kDim * kDim / 4, kDim * kDim / 4, kDim * kDim / 4};
  for (int i = 0; i < 6; ++i) { cv.src[i] = srcs[i]; cv.dst[i] = dsts[i]; cv.n4[i] = n4s[i]; }
  convert6<<<dim3(256, 6), 256, 0, stream>>>(cv);

  QKVArgs qa;
  qa.A[0] = cqf;  qa.A[1] = ckvf; qa.A[2] = ckvf;
  qa.W[0] = cWq;  qa.W[1] = cWk;  qa.W[2] = cWv;
  qa.bias[0] = bq; qa.bias[1] = bk; qa.bias[2] = bv;
  qa.rel = rel;
  qa.out[0] = q_buf; qa.out[1] = k_buf; qa.out[2] = vT_buf;
  qkv_gemm<<<dim3(kDim / 128, (kB * kNQ) / 128, 3), 256, 0, stream>>>(qa);

  attn32<<<kB * kHeads * (kNQ / 32), 512, 0, stream>>>(q_buf, k_buf, vT_buf, rel, ao_buf);

  o_gemm<<<dim3(kDim / 128, (kB * kNQ) / 128), 256, 0, stream>>>(ao_buf, cWo, bo, (float*)d_out);
}

// Round 5
// 250.562 us; speedup vs baseline: 1.1137x; 1.1137x over previous
//
#include <hip/hip_runtime.h>
#include <hip/hip_bf16.h>

typedef __bf16 bf16x8 __attribute__((ext_vector_type(8)));
typedef __bf16 bf16x4 __attribute__((ext_vector_type(4)));
typedef float  f32x4  __attribute__((ext_vector_type(4)));

#define MFMA_BF16(a, b, c) __builtin_amdgcn_mfma_f32_16x16x32_bf16((a), (b), (c), 0, 0, 0)

#define GLOAD_LDS16(g, l)                                          \
  __builtin_amdgcn_global_load_lds(                                \
      (const __attribute__((address_space(1))) void*)(g),          \
      (__attribute__((address_space(3))) void*)(l), 16, 0, 0)

static constexpr int kDim = 1024;
static constexpr int kHeads = 16;
static constexpr int kB = 4;
static constexpr int kNQ = 1024;
static constexpr int kNKV = 1024;

// ---------------------------------------------------------------------------
// fp32 -> bf16 canonicalization (fp32 inputs confirmed r1/r2).
// ---------------------------------------------------------------------------
struct Conv6 {
  const float* src[6];
  __bf16* dst[6];
  int n4[6];
};
__global__ __launch_bounds__(256) void convert6(Conv6 a) {
  const int w = blockIdx.y;
  const float4* __restrict__ s = (const float4*)a.src[w];
  __bf16* __restrict__ d = a.dst[w];
  const int n4 = a.n4[w];
  const int stride = gridDim.x * blockDim.x;
  for (int i = blockIdx.x * blockDim.x + threadIdx.x; i < n4; i += stride) {
    const float4 v = s[i];
    bf16x4 o = {(__bf16)v.x, (__bf16)v.y, (__bf16)v.z, (__bf16)v.w};
    *(bf16x4*)(d + (size_t)i * 4) = o;
  }
}

// ---------------------------------------------------------------------------
// QKV NT-GEMM. r5: epilogue stages C-tile in LDS (stride 136 = 272B, keeps
// all access ~2-way) then stores 16B/lane in 256B contiguous segments.
// z=0: q[b][h][n][64]; z=1: k[b][h][n][64]*r; z=2: vT[b][h][64][n]*r.
// ---------------------------------------------------------------------------
struct QKVArgs {
  const __bf16* A[3];
  const __bf16* W[3];
  const float* bias[3];
  const float* rel;
  __bf16* out[3];
};

__global__ __launch_bounds__(256) void qkv_gemm(QKVArgs args) {
  constexpr int K = kDim;
  constexpr int CT_STRIDE = 136;  // elements; 272B rows -> 16B-aligned chunks
  __shared__ __bf16 As[128 * 32];
  __shared__ __bf16 Bs[128 * 32];
  __shared__ __bf16 Ct[128 * CT_STRIDE];  // 34 KB; total LDS 50 KB, 3 WG/CU ok
  const int z = blockIdx.z;  // 0=Q, 1=K, 2=V
  const __bf16* __restrict__ A = args.A[z];
  const __bf16* __restrict__ W = args.W[z];
  const float* __restrict__ bias = args.bias[z];
  const float* __restrict__ rel = args.rel;
  __bf16* __restrict__ out = args.out[z];

  const int tid = threadIdx.x;
  const int wave = tid >> 6, lane = tid & 63;
  const int lr = lane & 15, quad = lane >> 4;
  const int wm = (wave & 1) << 6, wn = (wave >> 1) << 6;
  const int m0 = blockIdx.y << 7, n0 = blockIdx.x << 7;
  const int bb = m0 >> 10;  // 128 | 1024 => constant per tile

  f32x4 acc[4][4] = {};

  for (int k0 = 0; k0 < K; k0 += 32) {
    __syncthreads();
#pragma unroll
    for (int i = 0; i < 2; ++i) {
      const int ch = tid + (i << 8);
      const int row = ch >> 2, col = (ch & 3) << 3;
      GLOAD_LDS16(A + (size_t)(m0 + row) * K + k0 + col, As + ch * 8);
      GLOAD_LDS16(W + (size_t)(n0 + row) * K + k0 + col, Bs + ch * 8);
    }
    __syncthreads();
    bf16x8 afr[4], bfr[4];
#pragma unroll
    for (int mi = 0; mi < 4; ++mi)
      afr[mi] = *(const bf16x8*)&As[(wm + mi * 16 + lr) * 32 + quad * 8];
#pragma unroll
    for (int ni = 0; ni < 4; ++ni)
      bfr[ni] = *(const bf16x8*)&Bs[(wn + ni * 16 + lr) * 32 + quad * 8];
#pragma unroll
    for (int mi = 0; mi < 4; ++mi)
#pragma unroll
      for (int ni = 0; ni < 4; ++ni)
        acc[mi][ni] = MFMA_BF16(afr[mi], bfr[ni], acc[mi][ni]);
  }

  // acc -> Ct (bias + rel applied). D layout: row=(lane>>4)*4+r, col=lane&15.
#pragma unroll
  for (int mi = 0; mi < 4; ++mi)
#pragma unroll
    for (int ni = 0; ni < 4; ++ni) {
      const int col_l = wn + ni * 16 + lr;
      const float bc = bias[n0 + col_l];
      const f32x4 v = acc[mi][ni];
      const int row0 = wm + mi * 16 + (quad << 2);
      if (z == 2) {
        const f32x4 r4 = *(const f32x4*)(rel + (bb << 10) + ((m0 + row0) & 1023));
        bf16x4 pk;
#pragma unroll
        for (int r = 0; r < 4; ++r) pk[r] = (__bf16)((v[r] + bc) * r4[r]);
        *(bf16x4*)&Ct[col_l * CT_STRIDE + row0] = pk;  // transposed tile
      } else if (z == 1) {
        const f32x4 r4 = *(const f32x4*)(rel + (bb << 10) + ((m0 + row0) & 1023));
#pragma unroll
        for (int r = 0; r < 4; ++r)
          Ct[(row0 + r) * CT_STRIDE + col_l] = (__bf16)((v[r] + bc) * r4[r]);
      } else {
#pragma unroll
        for (int r = 0; r < 4; ++r)
          Ct[(row0 + r) * CT_STRIDE + col_l] = (__bf16)(v[r] + bc);
      }
    }
  __syncthreads();

  // Cooperative coalesced store-out: 16B/lane, 256B contiguous per 16 lanes.
  const int hh0 = n0 >> 6;
  if (z == 2) {
    // Ct[col][row]; out[((bb*16+hh)*64+dd)*1024 + nn]
#pragma unroll
    for (int j = 0; j < 8; ++j) {
      const int idx = (j << 8) + tid;
      const int c = idx >> 4, r8 = (idx & 15) << 3;
      const bf16x8 vv = *(const bf16x8*)&Ct[c * CT_STRIDE + r8];
      const int col = n0 + c;
      const int hh = col >> 6, dd = col & 63;
      *(bf16x8*)(out + ((size_t)(bb * kHeads + hh) * 64 + dd) * 1024 +
                 (m0 & 1023) + r8) = vv;
    }
  } else {
    // Ct[row][col]; out[(bb*16+hh)<<16 + nn*64 + dd]
#pragma unroll
    for (int j = 0; j < 8; ++j) {
      const int idx = (j << 8) + tid;
      const int r = idx >> 4, c8 = (idx & 15) << 3;
      const bf16x8 vv = *(const bf16x8*)&Ct[r * CT_STRIDE + c8];
      const int hh = hh0 + (c8 >> 6), dd = c8 & 63;
      *(bf16x8*)(out + ((size_t)(bb * kHeads + hh) << 16) +
                 (size_t)((m0 & 1023) + r) * 64 + dd) = vv;
    }
  }
}

// O-projection: fp32 output straight to d_out (unchanged).
__global__ __launch_bounds__(256) void o_gemm(const __bf16* __restrict__ A,
                                              const __bf16* __restrict__ W,
                                              const float* __restrict__ bias,
                                              float* __restrict__ out) {
  constexpr int K = kDim;
  __shared__ __bf16 As[128 * 32];
  __shared__ __bf16 Bs[128 * 32];
  const int tid = threadIdx.x;
  const int wave = tid >> 6, lane = tid & 63;
  const int lr = lane & 15, quad = lane >> 4;
  const int wm = (wave & 1) << 6, wn = (wave >> 1) << 6;
  const int m0 = blockIdx.y << 7, n0 = blockIdx.x << 7;

  f32x4 acc[4][4] = {};
  for (int k0 = 0; k0 < K; k0 += 32) {
    __syncthreads();
#pragma unroll
    for (int i = 0; i < 2; ++i) {
      const int ch = tid + (i << 8);
      const int row = ch >> 2, col = (ch & 3) << 3;
      GLOAD_LDS16(A + (size_t)(m0 + row) * K + k0 + col, As + ch * 8);
      GLOAD_LDS16(W + (size_t)(n0 + row) * K + k0 + col, Bs + ch * 8);
    }
    __syncthreads();
    bf16x8 afr[4], bfr[4];
#pragma unroll
    for (int mi = 0; mi < 4; ++mi)
      afr[mi] = *(const bf16x8*)&As[(wm + mi * 16 + lr) * 32 + quad * 8];
#pragma unroll
    for (int ni = 0; ni < 4; ++ni)
      bfr[ni] = *(const bf16x8*)&Bs[(wn + ni * 16 + lr) * 32 + quad * 8];
#pragma unroll
    for (int mi = 0; mi < 4; ++mi)
#pragma unroll
      for (int ni = 0; ni < 4; ++ni)
        acc[mi][ni] = MFMA_BF16(afr[mi], bfr[ni], acc[mi][ni]);
  }
#pragma unroll
  for (int mi = 0; mi < 4; ++mi)
#pragma unroll
    for (int ni = 0; ni < 4; ++ni) {
      const int col = n0 + wn + ni * 16 + lr;
      const float bc = bias[col];
      const f32x4 v = acc[mi][ni];
#pragma unroll
      for (int r = 0; r < 4; ++r) {
        const int row = m0 + wm + mi * 16 + (quad << 2) + r;
        out[(size_t)row * kDim + col] = v[r] + bc;
      }
    }
}

// ---------------------------------------------------------------------------
// Attention r5: r3 structure (256 thr, 4 waves; wave = d-tile in PV, both
// q-halves per wave) + r4's packed stores / no-logf + XCD head clustering
// (all 32 WGs of a head share bid%8 -> same XCD L2 holds its 256KB K/V) +
// register software-pipelining of K (phase 1) and V/S (phase 3).
// S[q][kv] bf16, chunk-XOR swizzle: addr = q*1024 + ((kv/8 ^ (q&7))*8 + kv%8.
// ---------------------------------------------------------------------------
__global__ __launch_bounds__(256, 2) void attn32(const __bf16* __restrict__ Qb,
                                                 const __bf16* __restrict__ Kb,
                                                 const __bf16* __restrict__ Vb,
                                                 const float* __restrict__ rel,
                                                 __bf16* __restrict__ AO) {
  __shared__ __bf16 S[32 * 1024];  // 64 KB
  const int tid = threadIdx.x;
  const int wave = tid >> 6, lane = tid & 63;
  const int lr = lane & 15, quad = lane >> 4;
  // XCD clustering: x = bid&7 (XCD), head = x + 8*(g>>5), qblk = g&31
  const int x = blockIdx.x & 7, g = blockIdx.x >> 3;
  const int hg = x + ((g >> 5) << 3);
  const int b = hg >> 4, h = hg & 15, q0 = (g & 31) << 5;
  const __bf16* Qh = Qb + ((size_t)(b * kHeads + h) << 16);  // [n][64]
  const __bf16* Kh = Kb + ((size_t)(b * kHeads + h) << 16);  // [n][64] (r folded)
  const __bf16* Vh = Vb + ((size_t)(b * kHeads + h) << 16);  // [64][n] (r folded)
  const float* rb = rel + (b << 10);

  // Q as B-fragments: B[n = q-row = lane&15][k = quad*8+j]
  bf16x8 qfrag[2][2];
#pragma unroll
  for (int mt = 0; mt < 2; ++mt) {
    const __bf16* qrow = Qh + (q0 + mt * 16 + lr) * 64 + quad * 8;
    qfrag[mt][0] = *(const bf16x8*)qrow;
    qfrag[mt][1] = *(const bf16x8*)(qrow + 32);
  }

  // Phase 1: D[kv][q] = K.Q^T; p = clip(r)*exp(s*0.125); pipelined K loads.
  {
    const __bf16* kp = Kh + ((wave << 4) + lr) * 64 + quad * 8;
    bf16x8 ka0 = *(const bf16x8*)kp;
    bf16x8 ka1 = *(const bf16x8*)(kp + 32);
    f32x4 rcv = *(const f32x4*)(rb + (wave << 4) + (quad << 2));
    for (int i = 0; i < 16; ++i) {
      bf16x8 kn0, kn1;
      f32x4 rn;
      if (i < 15) {  // prefetch next tile (independent of current compute)
        const int n1 = (((i + 1) << 2) + wave) << 4;
        const __bf16* kq = Kh + (n1 + lr) * 64 + quad * 8;
        kn0 = *(const bf16x8*)kq;
        kn1 = *(const bf16x8*)(kq + 32);
        rn = *(const f32x4*)(rb + n1 + (quad << 2));
      }
      const int n0 = ((i << 2) + wave) << 4;
      const int kvb = n0 + (quad << 2);
      const int cb = kvb >> 3, k7 = kvb & 7;
#pragma unroll
      for (int mt = 0; mt < 2; ++mt) {
        f32x4 acc = {0.f, 0.f, 0.f, 0.f};
        acc = MFMA_BF16(ka0, qfrag[mt][0], acc);
        acc = MFMA_BF16(ka1, qfrag[mt][1], acc);
        const int q = (mt << 4) + lr;  // D col = q-row
        bf16x4 pk;
#pragma unroll
        for (int r = 0; r < 4; ++r)    // D row = quad*4+r = kv
          pk[r] = (__bf16)(fmaxf(rcv[r], 1e-6f) * __expf(acc[r] * 0.125f));
        *(bf16x4*)&S[(q << 10) + ((cb ^ (q & 7)) << 3) + k7] = pk;
      }
      ka0 = kn0; ka1 = kn1; rcv = rn;
    }
  }
  __syncthreads();

  // Phase 3: wave = d-tile; both q-halves. O = P V'^T, L via ones-MFMA.
  bf16x8 ones;
#pragma unroll
  for (int j = 0; j < 8; ++j) ones[j] = (__bf16)1.0f;
  const int d0 = wave << 4;
  const __bf16* vrow = Vh + (size_t)(d0 + lr) * kNKV + (quad << 3);
  const int xr = lr & 7;
  f32x4 accO[2] = {{0.f, 0.f, 0.f, 0.f}, {0.f, 0.f, 0.f, 0.f}};
  f32x4 accL[2] = {{0.f, 0.f, 0.f, 0.f}, {0.f, 0.f, 0.f, 0.f}};
  bf16x8 bv = *(const bf16x8*)vrow;
  bf16x8 af[2];
  {
    const int c0 = quad;
#pragma unroll
    for (int mt = 0; mt < 2; ++mt)
      af[mt] = *(const bf16x8*)&S[(((mt << 4) + lr) << 10) + ((c0 ^ xr) << 3)];
  }
  for (int kk = 0; kk < 32; ++kk) {
    bf16x8 bvn, afn[2];
    if (kk < 31) {  // prefetch next V chunk + next S fragments
      bvn = *(const bf16x8*)(vrow + ((kk + 1) << 5));
      const int c1 = ((kk + 1) << 2) + quad;
#pragma unroll
      for (int mt = 0; mt < 2; ++mt)
        afn[mt] = *(const bf16x8*)&S[(((mt << 4) + lr) << 10) + ((c1 ^ xr) << 3)];
    }
#pragma unroll
    for (int mt = 0; mt < 2; ++mt) {
      accO[mt] = MFMA_BF16(af[mt], bv, accO[mt]);
      accL[mt] = MFMA_BF16(af[mt], ones, accL[mt]);
    }
    bv = bvn; af[0] = afn[0]; af[1] = afn[1];
  }
  const int dcol = (h << 6) + d0 + lr;
#pragma unroll
  for (int mt = 0; mt < 2; ++mt) {
    const size_t ob = (size_t)(b << 10) + q0 + (mt << 4);
#pragma unroll
    for (int r = 0; r < 4; ++r)
      AO[(ob + (quad << 2) + r) * kDim + dcol] = (__bf16)(accO[mt][r] / accL[mt][r]);
  }
}

extern "C" void kernel_launch(void* const* d_in, const int* in_sizes, int n_in,
                              void* d_out, int out_size, void* d_ws, size_t ws_size,
                              hipStream_t stream) {
  (void)in_sizes; (void)n_in; (void)out_size; (void)ws_size;
  const float* qf  = (const float*)d_in[0];
  const float* kvf = (const float*)d_in[1];
  const float* rel = (const float*)d_in[2];
  const float* Wq  = (const float*)d_in[3];
  const float* bq  = (const float*)d_in[4];
  const float* Wk  = (const float*)d_in[5];
  const float* bk  = (const float*)d_in[6];
  const float* Wv  = (const float*)d_in[7];
  const float* bv  = (const float*)d_in[8];
  const float* Wo  = (const float*)d_in[9];
  const float* bo  = (const float*)d_in[10];

  const size_t big = (size_t)kB * kNQ * kDim;  // 4M elements
  __bf16* p = (__bf16*)d_ws;
  __bf16* cqf  = p; p += big;
  __bf16* ckvf = p; p += big;
  __bf16* cWq  = p; p += kDim * kDim;
  __bf16* cWk  = p; p += kDim * kDim;
  __bf16* cWv  = p; p += kDim * kDim;
  __bf16* cWo  = p; p += kDim * kDim;
  __bf16* q_buf  = p; p += big;
  __bf16* k_buf  = p; p += big;
  __bf16* vT_buf = p; p += big;
  __bf16* ao_buf = p; p += big;

  Conv6 cv;
  const float* srcs[6] = {qf, kvf, Wq, Wk, Wv, Wo};
  __bf16* dsts[6] = {cqf, ckvf, cWq, cWk, cWv, cWo};
  const int n4s[6] = {(int)(big >> 2), (int)(big >> 2),
                      kDim * kDim / 4, kDim * kDim / 4, kDim * kDim / 4, kDim * kDim / 4};
  for (int i = 0; i < 6; ++i) { cv.src[i] = srcs[i]; cv.dst[i] = dsts[i]; cv.n4[i] = n4s[i]; }
  convert6<<<dim3(256, 6), 256, 0, stream>>>(cv);

  QKVArgs qa;
  qa.A[0] = cqf;  qa.A[1] = ckvf; qa.A[2] = ckvf;
  qa.W[0] = cWq;  qa.W[1] = cWk;  qa.W[2] = cWv;
  qa.bias[0] = bq; qa.bias[1] = bk; qa.bias[2] = bv;
  qa.rel = rel;
  qa.out[0] = q_buf; qa.out[1] = k_buf; qa.out[2] = vT_buf;
  qkv_gemm<<<dim3(kDim / 128, (kB * kNQ) / 128, 3), 256, 0, stream>>>(qa);

  attn32<<<kB * kHeads * (kNQ / 32), 256, 0, stream>>>(q_buf, k_buf, vT_buf, rel, ao_buf);

  o_gemm<<<dim3(kDim / 128, (kB * kNQ) / 128), 256, 0, stream>>>(ao_buf, cWo, bo, (float*)d_out);
}